// Round 1
// 388.335 us; speedup vs baseline: 1.0249x; 1.0249x over previous
//
#include <hip/hip_runtime.h>
#include <hip/hip_bf16.h>

using u16 = unsigned short;
using u32 = unsigned int;
using u64 = unsigned long long;

__device__ __forceinline__ float b2f(u16 u){
  union { u32 i; float f; } x; x.i = ((u32)u) << 16; return x.f;
}

// ---------------------------------------------------------------------------
// K0: detect container dtype (f32 vs packed bf16) in parallel + convert
// weights to f32.
__global__ __launch_bounds__(256) void k_prep(const void* __restrict__ data,
                                              const void* __restrict__ w0,
                                              const void* __restrict__ w1,
                                              const void* __restrict__ wl,
                                              int* __restrict__ gflag,
                                              float* __restrict__ w0f,
                                              float* __restrict__ w1f,
                                              float* __restrict__ wlf){
  __shared__ int zs[4], ss[4];
  __shared__ int sflag;
  int tid = threadIdx.x;
  u32 w = ((const u32*)data)[tid];
  u16 lo = (u16)(w & 0xFFFFu);
  u64 zb = __ballot(lo == 0);
  u64 sb = __ballot((lo >> 15) & 1);
  int wave = tid >> 6;
  if((tid & 63) == 0){ zs[wave] = __popcll(zb); ss[wave] = __popcll(sb); }
  __syncthreads();
  if(tid == 0){
    int zeros = zs[0]+zs[1]+zs[2]+zs[3];
    int signs = ss[0]+ss[1]+ss[2]+ss[3];
    int f = (zeros >= 128 || signs > 0) ? 1 : 0;
    sflag = f; *gflag = f;
  }
  __syncthreads();
  int f = sflag;
  const float* w0F = (const float*)w0; const u16* w0H = (const u16*)w0;
  const float* w1F = (const float*)w1; const u16* w1H = (const u16*)w1;
  const float* wlF = (const float*)wl; const u16* wlH = (const u16*)wl;
  for(int i = tid; i < 392;  i += 256) w0f[i] = f ? w0F[i] : b2f(w0H[i]);
  for(int i = tid; i < 1568; i += 256) w1f[i] = f ? w1F[i] : b2f(w1H[i]);
  for(int i = tid; i < 256;  i += 256) wlf[i] = f ? wlF[i] : b2f(wlH[i]);
}

// ---------------------------------------------------------------------------
// K1: data (4,2,256,256,100) -> P1 f32 (4,2,64,64,100), 4x4 avg pool,
// f64 accumulate (order unchanged).
__global__ __launch_bounds__(256) void k_pool1(const void* __restrict__ data,
                                               const int* __restrict__ gflag,
                                               float* __restrict__ P1){
  int idx = blockIdx.x * 256 + threadIdx.x;     // exact: 3200*256 = 819200
  int tc  = idx % 25;
  int pix = idx / 25;                           // nc*4096 + oh*64 + ow, nc<8
  int ow  = pix & 63;
  int oh  = (pix >> 6) & 63;
  int nc  = pix >> 12;
  int t0  = tc * 4;
  size_t off = ((size_t)((nc*256 + oh*4)*256 + ow*4)) * 100 + t0;
  double s0=0.0, s1=0.0, s2=0.0, s3=0.0;
  if(*gflag){
    const float* base = (const float*)data + off;
    #pragma unroll
    for(int di=0; di<4; ++di)
      #pragma unroll
      for(int dj=0; dj<4; ++dj){
        float4 v = *reinterpret_cast<const float4*>(base + (size_t)(di*256 + dj)*100);
        s0 += (double)v.x; s1 += (double)v.y; s2 += (double)v.z; s3 += (double)v.w;
      }
  } else {
    const u16* base = (const u16*)data + off;
    #pragma unroll
    for(int di=0; di<4; ++di)
      #pragma unroll
      for(int dj=0; dj<4; ++dj){
        ushort4 v = *reinterpret_cast<const ushort4*>(base + (size_t)(di*256 + dj)*100);
        s0 += (double)b2f(v.x); s1 += (double)b2f(v.y);
        s2 += (double)b2f(v.z); s3 += (double)b2f(v.w);
      }
  }
  float* o = P1 + (size_t)pix * 100 + t0;
  o[0] = (float)(s0 * 0.0625); o[1] = (float)(s1 * 0.0625);
  o[2] = (float)(s2 * 0.0625); o[3] = (float)(s3 * 0.0625);
}

// ---------------------------------------------------------------------------
// K2: conv1 7x7 pad3: P1 f32 x w0f -> A1 f32 (rounded-at-store; accumulate
// stays f64, same order). New layout: A1f4[((no*64 + tile)*25 + tb)*64 + lane]
// (float4 over the 4 t of a group). tile = (row>>2)*4 + colgrp,
// lane = (row&3)*16 + colin16 -> each wave's store is one contiguous 1KB.
__global__ __launch_bounds__(256) void k_conv1(const float* __restrict__ P1,
                                               const float* __restrict__ w0f,
                                               float* __restrict__ A1f){
  __shared__ float4  tile[968];   // [ci(2)][yy(22)][xx(22)] -> float4 over tt
  __shared__ double4 wl4[98];     // [ci*49+dy*7+dx] components = o
  int bid  = blockIdx.x;          // ((n*16 + tl)*25 + tcl)
  int tcl  = bid % 25; int rest = bid / 25;
  int tl   = rest & 15; int n = rest >> 4;
  int ty   = (tl >> 2) * 16, tx = (tl & 3) * 16;
  int t0   = tcl * 4;
  int tid  = threadIdx.x;
  for(int i = tid; i < 392; i += 256){
    int o = i / 98, r = i % 98;
    ((double*)wl4)[r*4 + o] = (double)w0f[i];
  }
  for(int idx = tid; idx < 968; idx += 256){
    int ci = idx / 484, r = idx % 484;
    int yy = r / 22, xx = r % 22;
    int gy = ty + yy - 3, gx = tx + xx - 3;
    float4 v; v.x = v.y = v.z = v.w = 0.f;
    if(gy >= 0 && gy < 64 && gx >= 0 && gx < 64){
      const float* p = P1 + ((size_t)((n*2+ci)*64 + gy)*64 + gx)*100 + t0;
      v.x = p[0]; v.y = p[1]; v.z = p[2]; v.w = p[3];
    }
    tile[idx] = v;
  }
  __syncthreads();
  int y = tid >> 4, x = tid & 15;
  double acc[4][4] = {};
  for(int ci = 0; ci < 2; ++ci)
    for(int dy = 0; dy < 7; ++dy){
      #pragma unroll
      for(int dx = 0; dx < 7; ++dx){
        float4 iv = tile[ci*484 + (y+dy)*22 + (x+dx)];
        double4 wv = wl4[ci*49 + dy*7 + dx];
        double i0 = (double)iv.x, i1 = (double)iv.y, i2 = (double)iv.z, i3 = (double)iv.w;
        acc[0][0] += wv.x*i0; acc[0][1] += wv.x*i1; acc[0][2] += wv.x*i2; acc[0][3] += wv.x*i3;
        acc[1][0] += wv.y*i0; acc[1][1] += wv.y*i1; acc[1][2] += wv.y*i2; acc[1][3] += wv.y*i3;
        acc[2][0] += wv.z*i0; acc[2][1] += wv.z*i1; acc[2][2] += wv.z*i2; acc[2][3] += wv.z*i3;
        acc[3][0] += wv.w*i0; acc[3][1] += wv.w*i1; acc[3][2] += wv.w*i2; acc[3][3] += wv.w*i3;
      }
    }
  // store: wave <-> scan tile bijection (row = ty+y, colgrp = tx>>4)
  int stile = (((ty + y) >> 2) << 2) + (tx >> 4);
  int lane  = ((y & 3) << 4) + x;
  float4* O = (float4*)A1f;
  size_t ob = ((size_t)(n*4)*64 + stile) * 25;     // per-o stride added below
  ob = (ob + tcl) * 64 + lane;
  #pragma unroll
  for(int o = 0; o < 4; ++o)
    O[ob + (size_t)o * 102400] = make_float4((float)acc[o][0], (float)acc[o][1],
                                             (float)acc[o][2], (float)acc[o][3]);
}

// ---------------------------------------------------------------------------
// K3: IAF spike scan + fused 4x4 pool. A1 now f32 float4 per lane per t-group
// -> one coalesced 1KB load per wave per group; 2-deep t-group prefetch.
// u/r update order per neuron unchanged (f64 membrane).
__global__ __launch_bounds__(64) void k_scan1(const float* __restrict__ A1f,
                                              float* __restrict__ S1p){
  int bid  = blockIdx.x;           // no*64 + tile
  int stile = bid & 63, no = bid >> 6;
  int xg = stile & 3, yg = stile >> 2;
  int lane = threadIdx.x;
  int lx = lane & 15;
  const float4* base = (const float4*)A1f + (size_t)bid * 1600 + lane;
  float* outb = S1p + (size_t)no*100*256 + yg*16 + xg*4;
  int cell = lx >> 2;
  u64 cmask = 0x000F000F000F000FULL << (4*cell);
  bool writer = (lane < 16) && ((lx & 3) == 0);
  double u = 0.0, r = 0.0;
  float4 cur = base[0];
  float4 nxt = base[64];
  for(int tb = 0; tb < 25; ++tb){
    int nb = (tb + 2 < 25) ? tb + 2 : 24;
    float4 nn = base[(size_t)nb * 64];
    #pragma unroll
    for(int j = 0; j < 4; ++j){
      double a = (j==0)?(double)cur.x:(j==1)?(double)cur.y:(j==2)?(double)cur.z:(double)cur.w;
      u += a;
      bool sp = (u + r >= 1.0);
      if(sp) r -= 1.0;
      u64 m = __ballot(sp);
      if(writer){
        float cnt = (float)__popcll(m & cmask);
        outb[(size_t)(tb*4 + j)*256 + cell] = cnt * 0.0625f;
      }
    }
    cur = nxt; nxt = nn;
  }
}

// ---------------------------------------------------------------------------
// K4: conv2 7x7 pad3: S1p f32 x w1f -> A2 f32 [(n*8+c)*25 + tb][px][tt]
// float4 stores (accumulate stays f64, same order).
__global__ __launch_bounds__(256) void k_conv2(const float* __restrict__ S1p,
                                               const float* __restrict__ w1f,
                                               float* __restrict__ A2f){
  __shared__ float   tf[4*4*484];   // [ci(4)][tt(4)][22][22]
  __shared__ double4 wl4[196];      // [ci*49+k] components = oj
  int bid = blockIdx.x;             // (n*25 + tc)*2 + oh
  int oh  = bid & 1; int rest = bid >> 1;
  int tc  = rest % 25; int n = rest / 25;
  int t0  = tc * 4;
  int tid = threadIdx.x;
  for(int i = tid; i < 7744; i += 256) tf[i] = 0.f;
  for(int i = tid; i < 784; i += 256){
    int oj = i / 196, rem = i % 196;
    ((double*)wl4)[rem*4 + oj] = (double)w1f[(oh*4 + oj)*196 + rem];
  }
  __syncthreads();
  for(int i = tid; i < 4096; i += 256){
    int ci = i >> 10, tt = (i >> 8) & 3, p = i & 255;
    int yy = p >> 4, xx = p & 15;
    tf[(ci*4 + tt)*484 + (yy+3)*22 + (xx+3)] =
        S1p[((size_t)(n*4+ci)*100 + t0 + tt)*256 + p];
  }
  __syncthreads();
  int y = tid >> 4, x = tid & 15;
  double acc[4][4] = {};
  for(int ci = 0; ci < 4; ++ci)
    for(int dy = 0; dy < 7; ++dy){
      #pragma unroll
      for(int dx = 0; dx < 7; ++dx){
        const float* tp = &tf[ci*1936 + (y+dy)*22 + (x+dx)];
        double4 wv = wl4[ci*49 + dy*7 + dx];
        double i0 = (double)tp[0],   i1 = (double)tp[484];
        double i2 = (double)tp[968], i3 = (double)tp[1452];
        acc[0][0] += wv.x*i0; acc[0][1] += wv.x*i1; acc[0][2] += wv.x*i2; acc[0][3] += wv.x*i3;
        acc[1][0] += wv.y*i0; acc[1][1] += wv.y*i1; acc[1][2] += wv.y*i2; acc[1][3] += wv.y*i3;
        acc[2][0] += wv.z*i0; acc[2][1] += wv.z*i1; acc[2][2] += wv.z*i2; acc[2][3] += wv.z*i3;
        acc[3][0] += wv.w*i0; acc[3][1] += wv.w*i1; acc[3][2] += wv.w*i2; acc[3][3] += wv.w*i3;
      }
    }
  float4* O = (float4*)A2f;
  size_t ob = ((size_t)(n*8 + oh*4)*25 + tc)*256 + tid;
  #pragma unroll
  for(int oj = 0; oj < 4; ++oj)
    O[ob + (size_t)oj*6400] = make_float4((float)acc[oj][0], (float)acc[oj][1],
                                          (float)acc[oj][2], (float)acc[oj][3]);
}

// ---------------------------------------------------------------------------
// K5: spike scan 2 + fused pool + einsum partials. f32 float4 loads,
// 2-deep t-group prefetch. u/r order unchanged.
__global__ __launch_bounds__(64) void k_scan2(const float* __restrict__ A2f,
                                              const float* __restrict__ wlf,
                                              float* __restrict__ P4){
  int bid  = blockIdx.x;          // nc*4 + q
  int q    = bid & 3, nc = bid >> 2, c = nc & 7;
  int lane = threadIdx.x;
  int px   = q*64 + lane;
  float w0g[4], w1g[4];
  #pragma unroll
  for(int g = 0; g < 4; ++g){
    w0g[g] = wlf[      c*16 + q*4 + g] * 0.0625f;
    w1g[g] = wlf[128 + c*16 + q*4 + g] * 0.0625f;
  }
  const float4* base = (const float4*)A2f + (size_t)nc*6400 + px;
  float* outb = P4 + (size_t)bid * 200;
  double u = 0.0, r = 0.0;
  float4 cur = base[0];
  float4 nxt = base[256];
  for(int tb = 0; tb < 25; ++tb){
    int nb = (tb + 2 < 25) ? tb + 2 : 24;
    float4 nn = base[(size_t)nb * 256];
    #pragma unroll
    for(int j = 0; j < 4; ++j){
      double a = (j==0)?(double)cur.x:(j==1)?(double)cur.y:(j==2)?(double)cur.z:(double)cur.w;
      u += a;
      bool sp = (u + r >= 1.0);
      if(sp) r -= 1.0;
      u64 m = __ballot(sp);
      if(lane == 0){
        float p0 = 0.f, p1 = 0.f;
        #pragma unroll
        for(int g = 0; g < 4; ++g){
          float cnt = (float)__popcll(m & (0x000F000F000F000FULL << (4*g)));
          p0 += cnt * w0g[g]; p1 += cnt * w1g[g];
        }
        int t = tb*4 + j;
        outb[t] = p0; outb[100 + t] = p1;
      }
    }
    cur = nxt; nxt = nn;
  }
}

// ---------------------------------------------------------------------------
// K6: reduce 32 partials per (n,o,t), store in detected container dtype.
__global__ __launch_bounds__(256) void k_out(const float* __restrict__ P4,
                                             const int* __restrict__ gflag,
                                             void* __restrict__ out){
  int idx = blockIdx.x * 256 + threadIdx.x;
  if(idx >= 800) return;
  int t = idx % 100; int o = (idx / 100) & 1; int n = idx / 200;
  float s = 0.f;
  for(int cq = 0; cq < 32; ++cq)
    s += P4[((size_t)(n*32 + cq))*200 + o*100 + t];
  if(*gflag) ((float*)out)[idx] = s;
  else       ((__hip_bfloat16*)out)[idx] = __float2bfloat16(s);
}

// ---------------------------------------------------------------------------
extern "C" void kernel_launch(void* const* d_in, const int* in_sizes, int n_in,
                              void* d_out, int out_size, void* d_ws, size_t ws_size,
                              hipStream_t stream) {
  const void* data = d_in[0];   // (4,2,256,256,100)
  const void* w0   = d_in[1];   // (4,2,7,7)
  const void* w1   = d_in[2];   // (8,4,7,7)
  const void* wl   = d_in[3];   // (2,8,4,4)
  char* ws = (char*)d_ws;
  // ws layout (bytes), peak ~41 MB:
  float*  P1   = (float*) (ws + 0);          // 13,107,200 B
  float*  A1f  = (float*) (ws + 13107200);   // 26,214,400 B (f32, retiled)
  float*  S1p  = (float*) (ws + 39321600);   //  1,638,400 B
  int*    gflag= (int*)   (ws + 40960000);   //          4 B
  float*  w0f  = (float*) (ws + 40960004);   //      1,568 B
  float*  w1f  = (float*) (ws + 40961572);   //      6,272 B
  float*  wlf  = (float*) (ws + 40967844);   //      1,024 B
  float*  A2f  = (float*) (ws + 0);          //  3,276,800 B (overlays P1; dead)
  float*  P4   = (float*) (ws + 3276800);    //    102,400 B

  hipLaunchKernelGGL(k_prep,  dim3(1),    dim3(256), 0, stream,
                     data, w0, w1, wl, gflag, w0f, w1f, wlf);
  hipLaunchKernelGGL(k_pool1, dim3(3200), dim3(256), 0, stream, data, gflag, P1);
  hipLaunchKernelGGL(k_conv1, dim3(1600), dim3(256), 0, stream, P1, w0f, A1f);
  hipLaunchKernelGGL(k_scan1, dim3(1024), dim3(64),  0, stream, A1f, S1p);
  hipLaunchKernelGGL(k_conv2, dim3(200),  dim3(256), 0, stream, S1p, w1f, A2f);
  hipLaunchKernelGGL(k_scan2, dim3(128),  dim3(64),  0, stream, A2f, wlf, P4);
  hipLaunchKernelGGL(k_out,   dim3(4),    dim3(256), 0, stream, P4, gflag, d_out);
}